// Round 1
// baseline (1600.842 us; speedup 1.0000x reference)
//
#include <hip/hip_runtime.h>
#include <hip/hip_bf16.h>
#include <cstdint>

// ---------------------------------------------------------------------------
// BaichuanAttention: hs[2048,5120] --W_pack--> qkv --ALiBi attn--> --W_o--> out
// Strategy: cast everything to bf16, MFMA GEMMs (m97 structure), flash attn.
// ---------------------------------------------------------------------------

typedef __attribute__((ext_vector_type(8))) short  bf16x8_t;  // 8 bf16 = 4 VGPR
typedef __attribute__((ext_vector_type(4))) float  f32x4_t;

#define S_LEN   2048
#define HIDDEN  5120
#define NHEADS  40
#define HDIM    128
#define QKV_N   15360
#define LOG2E   1.44269504088896f

// fp32 -> bf16 RNE, no dependence on __hip_bfloat16 internals
__device__ __forceinline__ unsigned short f2bf(float x) {
  unsigned u = __builtin_bit_cast(unsigned, x);
  u += 0x7fffu + ((u >> 16) & 1u);
  return (unsigned short)(u >> 16);
}

// async global->LDS, 16B per lane. LDS dest must be wave-uniform base.
__device__ __forceinline__ void gll16(const void* g, void* l) {
  __builtin_amdgcn_global_load_lds(
      (const __attribute__((address_space(1))) unsigned int*)g,
      (__attribute__((address_space(3))) unsigned int*)l, 16, 0, 0);
}

// ---------------------------------------------------------------------------
// cast fp32 -> bf16, 8 elems/thread, vectorized
// ---------------------------------------------------------------------------
__global__ void __launch_bounds__(256)
cast_f32_bf16(const float* __restrict__ in, unsigned short* __restrict__ out,
              const int n8) {
  const int i = blockIdx.x * 256 + threadIdx.x;
  if (i >= n8) return;
  const f32x4_t a = ((const f32x4_t*)in)[2 * i];
  const f32x4_t b = ((const f32x4_t*)in)[2 * i + 1];
  bf16x8_t o;
#pragma unroll
  for (int j = 0; j < 4; ++j) {
    o[j]     = (short)f2bf(a[j]);
    o[4 + j] = (short)f2bf(b[j]);
  }
  ((bf16x8_t*)out)[i] = o;
}

// ---------------------------------------------------------------------------
// GEMM  C[M][N] = A[M][K] * B[N][K]^T   (bf16 in, OutT out)
// m97 structure: 128x128 tile, BK=32, 4 waves (2x2), global_load_lds w=16.
// ---------------------------------------------------------------------------
template <typename OutT>
__global__ void __launch_bounds__(256, 2)
gemm_bt(const unsigned short* __restrict__ A, const unsigned short* __restrict__ B,
        OutT* __restrict__ C, const int M, const int N, const int K) {
  __shared__ unsigned short lA[128 * 32];
  __shared__ unsigned short lB[128 * 32];

  const int tid = threadIdx.x;
  const int wid = tid >> 6, lane = tid & 63;

  // XCD-bijective swizzle (grid is a multiple of 8 for all our calls)
  int wg = blockIdx.x;
  {
    const int nwg = gridDim.x;
    if ((nwg & 7) == 0) { const int cpx = nwg >> 3; wg = (wg & 7) * cpx + (wg >> 3); }
  }
  const int nbn = N >> 7;
  const int bi = wg / nbn, bj = wg % nbn;
  const int wr = wid >> 1, wc = wid & 1;
  const size_t sK = (size_t)K;

  // staging map: per gll call a wave covers 16 rows (4 lanes/row, 16B each)
  const int arow = wid * 16 + (lane >> 2);
  const int acol = (lane & 3) * 8;
  const unsigned short* gA0 = A + (size_t)(bi * 128 + arow) * sK + acol;
  const unsigned short* gB0 = B + (size_t)(bj * 128 + arow) * sK + acol;
  unsigned short* lA0 = &lA[wid * 16 * 32];
  unsigned short* lB0 = &lB[wid * 16 * 32];

  f32x4_t acc[4][4];
#pragma unroll
  for (int m = 0; m < 4; ++m)
#pragma unroll
    for (int n = 0; n < 4; ++n) acc[m][n] = (f32x4_t){0.f, 0.f, 0.f, 0.f};

  const int rs = (lane & 15) * 32 + (lane >> 4) * 8;  // frag read offset (elems)

  for (int k0 = 0; k0 < K; k0 += 32) {
    gll16(gA0 + k0,           lA0);
    gll16(gA0 + 64 * sK + k0, lA0 + 64 * 32);
    gll16(gB0 + k0,           lB0);
    gll16(gB0 + 64 * sK + k0, lB0 + 64 * 32);
    __syncthreads();  // drains vmcnt: tiles resident

    bf16x8_t a[4], b[4];
#pragma unroll
    for (int m = 0; m < 4; ++m) a[m] = *(const bf16x8_t*)&lA[(wr * 64 + m * 16) * 32 + rs];
#pragma unroll
    for (int n = 0; n < 4; ++n) b[n] = *(const bf16x8_t*)&lB[(wc * 64 + n * 16) * 32 + rs];
#pragma unroll
    for (int m = 0; m < 4; ++m)
#pragma unroll
      for (int n = 0; n < 4; ++n)
        acc[m][n] = __builtin_amdgcn_mfma_f32_16x16x32_bf16(a[m], b[n], acc[m][n], 0, 0, 0);
    __syncthreads();  // before next stage overwrites LDS
  }

  // D layout: col = lane&15, row = (lane>>4)*4 + reg
  const int r0 = bi * 128 + wr * 64 + (lane >> 4) * 4;
  const int c0 = bj * 128 + wc * 64 + (lane & 15);
#pragma unroll
  for (int m = 0; m < 4; ++m)
#pragma unroll
    for (int n = 0; n < 4; ++n)
#pragma unroll
      for (int r = 0; r < 4; ++r) {
        const size_t idx = (size_t)(r0 + m * 16 + r) * N + (c0 + n * 16);
        if constexpr (sizeof(OutT) == 2) C[idx] = (OutT)f2bf(acc[m][n][r]);
        else                             C[idx] = acc[m][n][r];
      }
}

// ---------------------------------------------------------------------------
// Flash attention with ALiBi + causal. One block = 128 q rows of one head.
// 4 waves, each owns 32 q rows. K tiles of 64. Everything bf16-MFMA,
// softmax state fp32 in registers.
// LDS: K [64][128] (XOR-swz), V^T [128][64] (XOR-swz), P [128][64] (XOR-swz).
// ---------------------------------------------------------------------------
__global__ void __launch_bounds__(256, 2)
attn_kernel(const unsigned short* __restrict__ qkv, unsigned short* __restrict__ ao) {
  __shared__ unsigned short Kl[64 * 128];
  __shared__ unsigned short Vt[128 * 64];
  __shared__ unsigned short Pl[128 * 64];

  const int tid = threadIdx.x;
  const int wid = tid >> 6, lane = tid & 63;
  const int g = lane >> 4, li = lane & 15;
  const int qb = blockIdx.x;   // 0..15
  const int h  = blockIdx.y;   // 0..39

  // ALiBi slopes: h<32: 2^(-0.25*(h+1)); else 2^(-0.125*(2*(h-32)+1))
  const float slope = (h < 32) ? exp2f(-0.25f * (float)(h + 1))
                               : exp2f(-0.125f * (float)(2 * (h - 32) + 1));
  const float scale = 0.08838834764831845f;  // 1/sqrt(128)

  const unsigned short* Qg = qkv + (size_t)h * HDIM;
  const unsigned short* Kg = qkv + HIDDEN + (size_t)h * HDIM;
  const unsigned short* Vg = qkv + 2 * HIDDEN + (size_t)h * HDIM;

  const int q0 = qb * 128 + wid * 32;  // wave's first q row

  // Q fragments held in registers: A-frag row = li, k = g*8+j within 32-window
  bf16x8_t qf[2][4];
#pragma unroll
  for (int m = 0; m < 2; ++m)
#pragma unroll
    for (int ds = 0; ds < 4; ++ds)
      qf[m][ds] = *(const bf16x8_t*)&Qg[(size_t)(q0 + m * 16 + li) * QKV_N + ds * 32 + g * 8];

  f32x4_t o_acc[2][8];
  float m_run[2][4], l_run[2][4];
#pragma unroll
  for (int m = 0; m < 2; ++m) {
#pragma unroll
    for (int nn = 0; nn < 8; ++nn) o_acc[m][nn] = (f32x4_t){0.f, 0.f, 0.f, 0.f};
#pragma unroll
    for (int r = 0; r < 4; ++r) { m_run[m][r] = -INFINITY; l_run[m][r] = 0.f; }
  }

  const int ntiles = 2 * qb + 2;
  for (int t = 0; t < ntiles; ++t) {
    const int kt = t * 64;
    __syncthreads();  // all waves done reading previous K/V tiles

    // ---- stage K [64][128] via global_load_lds: linear LDS dest,
    //      inverse-swizzled per-lane global source (rule 21)
#pragma unroll
    for (int c = 0; c < 4; ++c) {
      const int rowbase = c * 16 + wid * 4;
      const int row = rowbase + g;                      // this lane's row
      const int col = (li * 8) ^ ((row & 7) << 3);      // pre-swizzled source col
      gll16(&Kg[(size_t)(kt + row) * QKV_N + col], &Kl[rowbase * 128]);
    }
    // ---- stage V^T [128 d][64 k], reg-staged: coalesced 2B global reads
    //      (64 consecutive d per wave instr), swizzled b128 LDS writes
#pragma unroll
    for (int c = 0; c < 4; ++c) {
      const int e = c * 256 + tid;
      const int d = e & 127;
      const int k0 = (e >> 7) * 8;
      bf16x8_t pk;
#pragma unroll
      for (int j = 0; j < 8; ++j)
        pk[j] = (short)Vg[(size_t)(kt + k0 + j) * QKV_N + d];
      *(bf16x8_t*)((char*)Vt + (((d * 64 + k0) * 2) ^ ((d & 7) << 4))) = pk;
    }
    __syncthreads();  // staging visible

    // ---- S = Q K^T  (per wave: 32 q x 64 k)
    f32x4_t sacc[2][4];
#pragma unroll
    for (int m = 0; m < 2; ++m)
#pragma unroll
      for (int n = 0; n < 4; ++n) sacc[m][n] = (f32x4_t){0.f, 0.f, 0.f, 0.f};
#pragma unroll
    for (int ds = 0; ds < 4; ++ds) {
#pragma unroll
      for (int n = 0; n < 4; ++n) {
        const int row = n * 16 + li;
        const bf16x8_t kf = *(const bf16x8_t*)((const char*)Kl +
            (((row * 128 + ds * 32 + g * 8) * 2) ^ ((row & 7) << 4)));
#pragma unroll
        for (int m = 0; m < 2; ++m)
          sacc[m][n] = __builtin_amdgcn_mfma_f32_16x16x32_bf16(qf[m][ds], kf, sacc[m][n], 0, 0, 0);
      }
    }

    // ---- online softmax (row = q, spread over 16 lanes x 4 n), write P
    float corr[2][4];
#pragma unroll
    for (int m = 0; m < 2; ++m) {
#pragma unroll
      for (int r = 0; r < 4; ++r) {
        const int qg = q0 + m * 16 + g * 4 + r;
        float s[4];
#pragma unroll
        for (int n = 0; n < 4; ++n) {
          const int kg = kt + n * 16 + li;
          const float v = sacc[m][n][r] * scale - slope * (float)(qg - kg);
          s[n] = (kg <= qg) ? v : -INFINITY;
        }
        float mx = fmaxf(fmaxf(s[0], s[1]), fmaxf(s[2], s[3]));
#pragma unroll
        for (int off = 1; off < 16; off <<= 1) mx = fmaxf(mx, __shfl_xor(mx, off));
        const float mnew = fmaxf(m_run[m][r], mx);
        float p[4], psum = 0.f;
#pragma unroll
        for (int n = 0; n < 4; ++n) { p[n] = exp2f((s[n] - mnew) * LOG2E); psum += p[n]; }
#pragma unroll
        for (int off = 1; off < 16; off <<= 1) psum += __shfl_xor(psum, off);
        const float cr = exp2f((m_run[m][r] - mnew) * LOG2E);
        corr[m][r] = cr;
        l_run[m][r] = l_run[m][r] * cr + psum;
        m_run[m][r] = mnew;
        const int q = wid * 32 + m * 16 + g * 4 + r;
#pragma unroll
        for (int n = 0; n < 4; ++n) {
          const int kc = n * 16 + li;
          Pl[(q * 64 + kc) ^ ((q & 7) << 3)] = f2bf(p[n]);
        }
      }
    }
    // rescale O by corr
#pragma unroll
    for (int m = 0; m < 2; ++m)
#pragma unroll
      for (int nn = 0; nn < 8; ++nn)
#pragma unroll
        for (int r = 0; r < 4; ++r) o_acc[m][nn][r] *= corr[m][r];

    // ---- O += P V   (P: A-operand from Pl; V^T: B-operand from Vt)
#pragma unroll
    for (int ks = 0; ks < 2; ++ks) {
      bf16x8_t pf[2];
#pragma unroll
      for (int m = 0; m < 2; ++m) {
        const int q = wid * 32 + m * 16 + li;
        pf[m] = *(const bf16x8_t*)((const char*)Pl +
            (((q * 64 + ks * 32 + g * 8) * 2) ^ ((q & 7) << 4)));
      }
#pragma unroll
      for (int nn = 0; nn < 8; ++nn) {
        const int d = nn * 16 + li;
        const bf16x8_t vf = *(const bf16x8_t*)((const char*)Vt +
            (((d * 64 + ks * 32 + g * 8) * 2) ^ ((d & 7) << 4)));
#pragma unroll
        for (int m = 0; m < 2; ++m)
          o_acc[m][nn] = __builtin_amdgcn_mfma_f32_16x16x32_bf16(pf[m], vf, o_acc[m][nn], 0, 0, 0);
      }
    }
  }

  // ---- epilogue: ao[q][h*128+d] = O / l   (bf16)
#pragma unroll
  for (int m = 0; m < 2; ++m)
#pragma unroll
    for (int r = 0; r < 4; ++r) {
      const float inv = 1.0f / l_run[m][r];
      const int qg = q0 + m * 16 + g * 4 + r;
#pragma unroll
      for (int nn = 0; nn < 8; ++nn) {
        const int d = nn * 16 + li;
        ao[(size_t)qg * HIDDEN + h * HDIM + d] = f2bf(o_acc[m][nn][r] * inv);
      }
    }
}

// ---------------------------------------------------------------------------
// launch
// ---------------------------------------------------------------------------
extern "C" void kernel_launch(void* const* d_in, const int* in_sizes, int n_in,
                              void* d_out, int out_size, void* d_ws, size_t ws_size,
                              hipStream_t stream) {
  const float* hs = (const float*)d_in[0];   // [2048,5120]
  const float* wp = (const float*)d_in[1];   // [15360,5120]
  const float* wo = (const float*)d_in[2];   // [5120,5120]
  float* out = (float*)d_out;                // [2048,5120] fp32

  char* ws = (char*)d_ws;
  // layout (bytes):
  //   [0, 157286400)            w_pack bf16  (later reused for w_o bf16)
  //   [157286400, 178257920)    hidden bf16
  //   [178257920, 241172480)    qkv bf16 [2048][15360]
  //   [241172480, 262144000)    attn out bf16 [2048][5120]
  unsigned short* wpb = (unsigned short*)(ws);
  unsigned short* hsb = (unsigned short*)(ws + 157286400);
  unsigned short* qkv = (unsigned short*)(ws + 178257920);
  unsigned short* ao  = (unsigned short*)(ws + 241172480);
  unsigned short* wob = (unsigned short*)(ws);  // reuse after QKV GEMM

  // casts (counts are in 8-element chunks)
  cast_f32_bf16<<<38400, 256, 0, stream>>>(wp, wpb, 9830400);
  cast_f32_bf16<<<5120, 256, 0, stream>>>(hs, hsb, 1310720);

  // QKV projection: [2048,15360] = hs * w_pack^T
  gemm_bt<unsigned short><<<16 * 120, 256, 0, stream>>>(hsb, wpb, qkv, S_LEN, QKV_N, HIDDEN);

  // w_o cast (reuses w_pack region, safe after QKV GEMM in stream order)
  cast_f32_bf16<<<12800, 256, 0, stream>>>(wo, wob, 3276800);

  // attention
  attn_kernel<<<dim3(16, NHEADS), 256, 0, stream>>>(qkv, ao);

  // o_proj: out = ao * w_o^T  (fp32 out)
  gemm_bt<float><<<16 * 40, 256, 0, stream>>>(ao, wob, out, S_LEN, HIDDEN, HIDDEN);
}

// Round 2
// 1524.511 us; speedup vs baseline: 1.0501x; 1.0501x over previous
//
#include <hip/hip_runtime.h>
#include <hip/hip_bf16.h>
#include <cstdint>

// ---------------------------------------------------------------------------
// BaichuanAttention: hs[2048,5120] --W_pack--> qkv --ALiBi attn--> --W_o--> out
// Round 2: split-KV flash attention (balanced grid), double-buffered staging
// with 1 barrier/tile, V pre-transposed for clean gll16 staging.
// ---------------------------------------------------------------------------

typedef __attribute__((ext_vector_type(8))) short  bf16x8_t;  // 8 bf16 = 4 VGPR
typedef __attribute__((ext_vector_type(4))) float  f32x4_t;

#define S_LEN   2048
#define HIDDEN  5120
#define NHEADS  40
#define HDIM    128
#define QKV_N   15360
#define LOG2E   1.44269504088896f

// fp32 -> bf16 RNE
__device__ __forceinline__ unsigned short f2bf(float x) {
  unsigned u = __builtin_bit_cast(unsigned, x);
  u += 0x7fffu + ((u >> 16) & 1u);
  return (unsigned short)(u >> 16);
}

// async global->LDS, 16B per lane. LDS dest wave-uniform base + lane*16.
__device__ __forceinline__ void gll16(const void* g, void* l) {
  __builtin_amdgcn_global_load_lds(
      (const __attribute__((address_space(1))) unsigned int*)g,
      (__attribute__((address_space(3))) unsigned int*)l, 16, 0, 0);
}

// ---------------------------------------------------------------------------
// cast fp32 -> bf16, 8 elems/thread
// ---------------------------------------------------------------------------
__global__ void __launch_bounds__(256)
cast_f32_bf16(const float* __restrict__ in, unsigned short* __restrict__ out,
              const int n8) {
  const int i = blockIdx.x * 256 + threadIdx.x;
  if (i >= n8) return;
  const f32x4_t a = ((const f32x4_t*)in)[2 * i];
  const f32x4_t b = ((const f32x4_t*)in)[2 * i + 1];
  bf16x8_t o;
#pragma unroll
  for (int j = 0; j < 4; ++j) {
    o[j]     = (short)f2bf(a[j]);
    o[4 + j] = (short)f2bf(b[j]);
  }
  ((bf16x8_t*)out)[i] = o;
}

// ---------------------------------------------------------------------------
// GEMM  C[M][N] = A[M][K] * B[N][K]^T  (m97 structure, unchanged from R1)
// ---------------------------------------------------------------------------
template <typename OutT>
__global__ void __launch_bounds__(256, 2)
gemm_bt(const unsigned short* __restrict__ A, const unsigned short* __restrict__ B,
        OutT* __restrict__ C, const int M, const int N, const int K) {
  __shared__ unsigned short lA[128 * 32];
  __shared__ unsigned short lB[128 * 32];

  const int tid = threadIdx.x;
  const int wid = tid >> 6, lane = tid & 63;

  int wg = blockIdx.x;
  {
    const int nwg = gridDim.x;
    if ((nwg & 7) == 0) { const int cpx = nwg >> 3; wg = (wg & 7) * cpx + (wg >> 3); }
  }
  const int nbn = N >> 7;
  const int bi = wg / nbn, bj = wg % nbn;
  const int wr = wid >> 1, wc = wid & 1;
  const size_t sK = (size_t)K;

  const int arow = wid * 16 + (lane >> 2);
  const int acol = (lane & 3) * 8;
  const unsigned short* gA0 = A + (size_t)(bi * 128 + arow) * sK + acol;
  const unsigned short* gB0 = B + (size_t)(bj * 128 + arow) * sK + acol;
  unsigned short* lA0 = &lA[wid * 16 * 32];
  unsigned short* lB0 = &lB[wid * 16 * 32];

  f32x4_t acc[4][4];
#pragma unroll
  for (int m = 0; m < 4; ++m)
#pragma unroll
    for (int n = 0; n < 4; ++n) acc[m][n] = (f32x4_t){0.f, 0.f, 0.f, 0.f};

  const int rs = (lane & 15) * 32 + (lane >> 4) * 8;

  for (int k0 = 0; k0 < K; k0 += 32) {
    gll16(gA0 + k0,           lA0);
    gll16(gA0 + 64 * sK + k0, lA0 + 64 * 32);
    gll16(gB0 + k0,           lB0);
    gll16(gB0 + 64 * sK + k0, lB0 + 64 * 32);
    __syncthreads();

    bf16x8_t a[4], b[4];
#pragma unroll
    for (int m = 0; m < 4; ++m) a[m] = *(const bf16x8_t*)&lA[(wr * 64 + m * 16) * 32 + rs];
#pragma unroll
    for (int n = 0; n < 4; ++n) b[n] = *(const bf16x8_t*)&lB[(wc * 64 + n * 16) * 32 + rs];
#pragma unroll
    for (int m = 0; m < 4; ++m)
#pragma unroll
      for (int n = 0; n < 4; ++n)
        acc[m][n] = __builtin_amdgcn_mfma_f32_16x16x32_bf16(a[m], b[n], acc[m][n], 0, 0, 0);
    __syncthreads();
  }

  const int r0 = bi * 128 + wr * 64 + (lane >> 4) * 4;
  const int c0 = bj * 128 + wc * 64 + (lane & 15);
#pragma unroll
  for (int m = 0; m < 4; ++m)
#pragma unroll
    for (int n = 0; n < 4; ++n)
#pragma unroll
      for (int r = 0; r < 4; ++r) {
        const size_t idx = (size_t)(r0 + m * 16 + r) * N + (c0 + n * 16);
        if constexpr (sizeof(OutT) == 2) C[idx] = (OutT)f2bf(acc[m][n][r]);
        else                             C[idx] = acc[m][n][r];
      }
}

// ---------------------------------------------------------------------------
// V transpose: vT[h*128+d][s] = qkv[s][2H + h*128 + d]. 64x64 LDS tiles.
// ---------------------------------------------------------------------------
__global__ void __launch_bounds__(256)
transpose_v(const unsigned short* __restrict__ qkv, unsigned short* __restrict__ vT) {
  __shared__ unsigned short t[64][72];  // +8 pad; 144B row stride (16B-aligned)
  const int s0 = blockIdx.x * 64;
  const int d0 = blockIdx.y * 64;
  const int r = threadIdx.x >> 3, c8 = (threadIdx.x & 7) * 8;
#pragma unroll
  for (int rr = 0; rr < 64; rr += 32) {
    bf16x8_t v = *(const bf16x8_t*)&qkv[(size_t)(s0 + r + rr) * QKV_N + 2 * HIDDEN + d0 + c8];
    *(bf16x8_t*)&t[r + rr][c8] = v;
  }
  __syncthreads();
#pragma unroll
  for (int rr = 0; rr < 64; rr += 32) {
    const int dd = r + rr;
    bf16x8_t o;
#pragma unroll
    for (int j = 0; j < 8; ++j) o[j] = (short)t[c8 + j][dd];
    *(bf16x8_t*)&vT[(size_t)(d0 + dd) * S_LEN + s0 + c8] = o;
  }
}

// ---------------------------------------------------------------------------
// Split-KV flash attention with ALiBi + causal.
// Grid: 1600 blocks = (head, q-tile qt of 128, kv-chunk kc of 512).
// 4 waves x 32 q rows. KV tiles of 64, double-buffered, 1 barrier/tile.
// Outputs UNNORMALIZED partial O (fp32) + per-row (m, l).
// ---------------------------------------------------------------------------
__global__ void __launch_bounds__(256, 2)
attn_split(const unsigned short* __restrict__ qkv, const unsigned short* __restrict__ vT,
           float* __restrict__ Opart, float* __restrict__ Ml) {
  __shared__ unsigned short Kl[2][64 * 128];  // 32 KB, XOR-swizzled rows
  __shared__ unsigned short Vt[2][128 * 64];  // 32 KB, XOR-swizzled rows
  __shared__ unsigned short Pl[128 * 64];     // 16 KB, per-wave private rows

  const int tid = threadIdx.x;
  const int wid = tid >> 6, lane = tid & 63;
  const int g = lane >> 4, li = lane & 15;

  // XCD-bijective swizzle (1600 % 8 == 0): same-head slots cluster per XCD
  int slot = blockIdx.x;
  { const int cpx = 1600 >> 3; slot = (slot & 7) * cpx + (slot >> 3); }
  const int h = slot / 40, rr_ = slot % 40;
  int qt, kc;
  if      (rr_ < 4)  { qt = rr_;                 kc = 0; }
  else if (rr_ < 12) { qt = 4 + ((rr_ - 4) >> 1);  kc = (rr_ - 4) & 1; }
  else if (rr_ < 24) { qt = 8 + (rr_ - 12) / 3;    kc = (rr_ - 12) % 3; }
  else               { qt = 12 + ((rr_ - 24) >> 2); kc = (rr_ - 24) & 3; }
  const int kvs = kc * 512;
  const int kvend_full = (qt + 1) * 128;
  const int kvend = (kvend_full < kvs + 512) ? kvend_full : (kvs + 512);
  const int ntiles = (kvend - kvs) >> 6;

  const float slope = (h < 32) ? exp2f(-0.25f * (float)(h + 1))
                               : exp2f(-0.125f * (float)(2 * (h - 32) + 1));
  const float scale = 0.08838834764831845f;  // 1/sqrt(128)

  const unsigned short* Qg = qkv + (size_t)h * HDIM;
  const unsigned short* Kg = qkv + HIDDEN + (size_t)h * HDIM;
  const unsigned short* Vh = vT + (size_t)h * HDIM * S_LEN;

  const int q0 = qt * 128 + wid * 32;

  // Q fragments in registers
  bf16x8_t qf[2][4];
#pragma unroll
  for (int m = 0; m < 2; ++m)
#pragma unroll
    for (int ds = 0; ds < 4; ++ds)
      qf[m][ds] = *(const bf16x8_t*)&Qg[(size_t)(q0 + m * 16 + li) * QKV_N + ds * 32 + g * 8];

  f32x4_t o_acc[2][8];
  float m_run[2][4], l_run[2][4];
#pragma unroll
  for (int m = 0; m < 2; ++m) {
#pragma unroll
    for (int nn = 0; nn < 8; ++nn) o_acc[m][nn] = (f32x4_t){0.f, 0.f, 0.f, 0.f};
#pragma unroll
    for (int r = 0; r < 4; ++r) { m_run[m][r] = -INFINITY; l_run[m][r] = 0.f; }
  }

  // staging: K tile [64 k][128 d], V^T tile [128 d][64 k]; both swizzled via
  // linear LDS dest + inverse-swizzled per-lane global source (rule 21).
  auto stageK = [&](int buf, int t) {
#pragma unroll
    for (int c = 0; c < 4; ++c) {
      const int rowbase = c * 16 + wid * 4;
      const int row = rowbase + g;
      const int col = (li * 8) ^ ((row & 7) << 3);
      gll16(&Kg[(size_t)(kvs + t * 64 + row) * QKV_N + col], &Kl[buf][rowbase * 128]);
    }
  };
  auto stageV = [&](int buf, int t) {
#pragma unroll
    for (int c = 0; c < 4; ++c) {
      const int rowbase = c * 32 + wid * 8;
      const int row = rowbase + (lane >> 3);  // d index
      const int col = ((lane & 7) ^ (row & 7)) * 8;
      gll16(&Vh[(size_t)row * S_LEN + kvs + t * 64 + col], &Vt[buf][rowbase * 64]);
    }
  };

  stageK(0, 0);
  stageV(0, 0);
  __syncthreads();  // drains vmcnt: tile 0 resident

  for (int t = 0; t < ntiles; ++t) {
    const int cur = t & 1;
    if (t + 1 < ntiles) { stageK(cur ^ 1, t + 1); stageV(cur ^ 1, t + 1); }
    const int kt = kvs + t * 64;

    // ---- S = Q K^T
    f32x4_t sacc[2][4];
#pragma unroll
    for (int m = 0; m < 2; ++m)
#pragma unroll
      for (int n = 0; n < 4; ++n) sacc[m][n] = (f32x4_t){0.f, 0.f, 0.f, 0.f};
#pragma unroll
    for (int ds = 0; ds < 4; ++ds) {
#pragma unroll
      for (int n = 0; n < 4; ++n) {
        const int row = n * 16 + li;
        const bf16x8_t kf = *(const bf16x8_t*)((const char*)&Kl[cur][0] +
            (((row * 128 + ds * 32 + g * 8) * 2) ^ ((row & 7) << 4)));
#pragma unroll
        for (int m = 0; m < 2; ++m)
          sacc[m][n] = __builtin_amdgcn_mfma_f32_16x16x32_bf16(qf[m][ds], kf, sacc[m][n], 0, 0, 0);
      }
    }

    // ---- online softmax, write P
    float corr[2][4];
#pragma unroll
    for (int m = 0; m < 2; ++m) {
#pragma unroll
      for (int r = 0; r < 4; ++r) {
        const int qg = q0 + m * 16 + g * 4 + r;
        float s[4];
#pragma unroll
        for (int n = 0; n < 4; ++n) {
          const int kg = kt + n * 16 + li;
          const float v = sacc[m][n][r] * scale - slope * (float)(qg - kg);
          s[n] = (kg <= qg) ? v : -INFINITY;
        }
        float mx = fmaxf(fmaxf(s[0], s[1]), fmaxf(s[2], s[3]));
#pragma unroll
        for (int off = 1; off < 16; off <<= 1) mx = fmaxf(mx, __shfl_xor(mx, off));
        const float mnew = fmaxf(m_run[m][r], mx);
        float p[4], psum = 0.f;
#pragma unroll
        for (int n = 0; n < 4; ++n) { p[n] = exp2f((s[n] - mnew) * LOG2E); psum += p[n]; }
#pragma unroll
        for (int off = 1; off < 16; off <<= 1) psum += __shfl_xor(psum, off);
        const float cr = exp2f((m_run[m][r] - mnew) * LOG2E);
        corr[m][r] = cr;
        l_run[m][r] = l_run[m][r] * cr + psum;
        m_run[m][r] = mnew;
        const int q = wid * 32 + m * 16 + g * 4 + r;
#pragma unroll
        for (int n = 0; n < 4; ++n) {
          const int kcl = n * 16 + li;
          Pl[(q * 64 + kcl) ^ ((q & 7) << 3)] = f2bf(p[n]);
        }
      }
    }
#pragma unroll
    for (int m = 0; m < 2; ++m)
#pragma unroll
      for (int nn = 0; nn < 8; ++nn)
#pragma unroll
        for (int r = 0; r < 4; ++r) o_acc[m][nn][r] *= corr[m][r];

    // ---- O += P V
#pragma unroll
    for (int ks = 0; ks < 2; ++ks) {
      bf16x8_t pf[2];
#pragma unroll
      for (int m = 0; m < 2; ++m) {
        const int q = wid * 32 + m * 16 + li;
        pf[m] = *(const bf16x8_t*)((const char*)Pl +
            (((q * 64 + ks * 32 + g * 8) * 2) ^ ((q & 7) << 4)));
      }
#pragma unroll
      for (int nn = 0; nn < 8; ++nn) {
        const int d = nn * 16 + li;
        const bf16x8_t vf = *(const bf16x8_t*)((const char*)&Vt[cur][0] +
            (((d * 64 + ks * 32 + g * 8) * 2) ^ ((d & 7) << 4)));
#pragma unroll
        for (int m = 0; m < 2; ++m)
          o_acc[m][nn] = __builtin_amdgcn_mfma_f32_16x16x32_bf16(pf[m], vf, o_acc[m][nn], 0, 0, 0);
      }
    }
    __syncthreads();  // waves done with cur; next stage complete (vmcnt drain)
  }

  // ---- partial epilogue: unnormalized O (fp32) + (m, l) per row
  const int slotbase = slot;  // canonical slot id (post-decode == pre-swizzle map)
#pragma unroll
  for (int m = 0; m < 2; ++m)
#pragma unroll
    for (int r = 0; r < 4; ++r) {
      const int row = wid * 32 + m * 16 + g * 4 + r;
      if (li == 0) {
        Ml[(size_t)slotbase * 256 + row * 2 + 0] = m_run[m][r];
        Ml[(size_t)slotbase * 256 + row * 2 + 1] = l_run[m][r];
      }
#pragma unroll
      for (int nn = 0; nn < 8; ++nn) {
        const int d = nn * 16 + li;
        Opart[(size_t)slotbase * 16384 + row * 128 + d] = o_acc[m][nn][r];
      }
    }
}

// ---------------------------------------------------------------------------
// combine partials -> ao (bf16). Grid: 640 = (h, qt). 2 threads/row.
// ---------------------------------------------------------------------------
__global__ void __launch_bounds__(256)
combine_kernel(const float* __restrict__ Opart, const float* __restrict__ Ml,
               unsigned short* __restrict__ ao) {
  const int b = blockIdx.x;
  const int h = b >> 4, qt = b & 15;
  const int nc = (qt >> 2) + 1;
  const int base = (qt < 4) ? qt : (qt < 8) ? 4 + 2 * (qt - 4)
                 : (qt < 12) ? 12 + 3 * (qt - 8) : 24 + 4 * (qt - 12);
  const int slot0 = h * 40 + base;
  const int row = threadIdx.x >> 1, d0 = (threadIdx.x & 1) * 64;

  float mi[4], li_[4];
  float M = -INFINITY;
#pragma unroll
  for (int i = 0; i < 4; ++i) {
    if (i < nc) {
      mi[i]  = Ml[(size_t)(slot0 + i) * 256 + row * 2 + 0];
      li_[i] = Ml[(size_t)(slot0 + i) * 256 + row * 2 + 1];
      M = fmaxf(M, mi[i]);
    }
  }
  float w[4], L = 0.f;
#pragma unroll
  for (int i = 0; i < 4; ++i) {
    w[i] = (i < nc) ? exp2f((mi[i] - M) * LOG2E) : 0.f;
    if (i < nc) L += w[i] * li_[i];
  }
  const float inv = 1.0f / L;
  const size_t orow = (size_t)(qt * 128 + row) * HIDDEN + h * HDIM;

  for (int dd = d0; dd < d0 + 64; dd += 4) {
    f32x4_t acc = (f32x4_t){0.f, 0.f, 0.f, 0.f};
#pragma unroll
    for (int i = 0; i < 4; ++i) {
      if (i < nc) {
        const f32x4_t o = *(const f32x4_t*)&Opart[(size_t)(slot0 + i) * 16384 + row * 128 + dd];
#pragma unroll
        for (int j = 0; j < 4; ++j) acc[j] += w[i] * o[j];
      }
    }
#pragma unroll
    for (int j = 0; j < 4; ++j) ao[orow + dd + j] = f2bf(acc[j] * inv);
  }
}

// ---------------------------------------------------------------------------
// launch
// ---------------------------------------------------------------------------
extern "C" void kernel_launch(void* const* d_in, const int* in_sizes, int n_in,
                              void* d_out, int out_size, void* d_ws, size_t ws_size,
                              hipStream_t stream) {
  const float* hs = (const float*)d_in[0];   // [2048,5120]
  const float* wp = (const float*)d_in[1];   // [15360,5120]
  const float* wo = (const float*)d_in[2];   // [5120,5120]
  float* out = (float*)d_out;                // [2048,5120] fp32

  char* ws = (char*)d_ws;
  // layout (bytes), lifetime-disjoint overlaps annotated:
  //   [0, 157286400)           wpb (dead after QKV GEMM)
  //     [0, 52428800)            wob  (cast after QKV GEMM)
  //     [52428800, 157286400)    Opart fp32 (attn partials, 1600x128x128)
  //   [157286400, 178257920)   hsb (dead after QKV GEMM)
  //     [157286400, 158924800)   Ml fp32 (1600x128x2)
  //   [178257920, 241172480)   qkv bf16 [2048][15360]
  //   [241172480, 262144000)   ao bf16 [2048][5120]
  // vT bf16 [5120][2048] lives in d_out (dead until o_proj overwrites it).
  unsigned short* wpb = (unsigned short*)(ws);
  unsigned short* hsb = (unsigned short*)(ws + 157286400);
  unsigned short* qkv = (unsigned short*)(ws + 178257920);
  unsigned short* ao  = (unsigned short*)(ws + 241172480);
  unsigned short* wob = (unsigned short*)(ws);
  float* Opart = (float*)(ws + 52428800);
  float* Ml    = (float*)(ws + 157286400);
  unsigned short* vTb = (unsigned short*)d_out;

  cast_f32_bf16<<<38400, 256, 0, stream>>>(wp, wpb, 9830400);
  cast_f32_bf16<<<5120, 256, 0, stream>>>(hs, hsb, 1310720);

  // QKV projection: [2048,15360] = hs * w_pack^T
  gemm_bt<unsigned short><<<1920, 256, 0, stream>>>(hsb, wpb, qkv, S_LEN, QKV_N, HIDDEN);

  cast_f32_bf16<<<12800, 256, 0, stream>>>(wo, wob, 3276800);

  // V transpose into d_out scratch
  transpose_v<<<dim3(32, 80), 256, 0, stream>>>(qkv, vTb);

  // split-KV attention -> partials
  attn_split<<<1600, 256, 0, stream>>>(qkv, vTb, Opart, Ml);

  // merge partials -> ao
  combine_kernel<<<640, 256, 0, stream>>>(Opart, Ml, ao);

  // o_proj: out = ao * w_o^T (fp32), overwrites d_out (vT dead)
  gemm_bt<float><<<640, 256, 0, stream>>>(ao, wob, out, S_LEN, HIDDEN, HIDDEN);
}